// Round 1
// baseline (644.899 us; speedup 1.0000x reference)
//
#include <hip/hip_runtime.h>
#include <stdint.h>
#include <math.h>

typedef short    s16x8 __attribute__((ext_vector_type(8)));
typedef float    f32x4 __attribute__((ext_vector_type(4)));
typedef uint32_t u32x4 __attribute__((ext_vector_type(4)));
typedef unsigned short u16x4 __attribute__((ext_vector_type(4)));
typedef unsigned short u16x8 __attribute__((ext_vector_type(8)));

__device__ __forceinline__ uint16_t f2bf(float f) {
  union { float f; uint32_t u; } v; v.f = f;
  uint32_t r = v.u + 0x7fffu + ((v.u >> 16) & 1u);
  return (uint16_t)(r >> 16);
}
__device__ __forceinline__ float bf2f(uint16_t h) {
  union { uint32_t u; float f; } v; v.u = ((uint32_t)h) << 16;
  return v.f;
}

// async global->LDS, 16B per lane; LDS dest = wave-uniform base + lane*16
__device__ __forceinline__ void gld16(const void* g, void* l) {
  __builtin_amdgcn_global_load_lds(
      (const __attribute__((address_space(1))) void*)g,
      (__attribute__((address_space(3))) void*)l, 16, 0, 0);
}

// ---------------- K0: x fp32 -> xf bf16 (2048 x 4096); also zeroes rs ----------------
__global__ __launch_bounds__(256) void cvt_x(const float* __restrict__ x,
                                             uint16_t* __restrict__ xf,
                                             float* __restrict__ rs) {
  if (blockIdx.x < 64) rs[blockIdx.x * 256 + threadIdx.x] = 0.f;
  size_t i = ((size_t)blockIdx.x * 256 + threadIdx.x) * 4;
  f32x4 v = *(const f32x4*)(x + i);
  u16x4 o = { f2bf(v.x), f2bf(v.y), f2bf(v.z), f2bf(v.w) };
  *(u16x4*)(xf + i) = o;
}

// ------------- K1: W (3 x H x 4096 x 512 fp32) -> Wt (24 x 512 x 4096 bf16) -------------
// 64(f) x 32(u) tiles; writes are full 16B u16x8 -> coalesced 128B per u-row.
__global__ __launch_bounds__(256) void wtrans(const float* __restrict__ W0,
                                              const float* __restrict__ W1,
                                              const float* __restrict__ W2,
                                              uint16_t* __restrict__ Wt) {
  const int z = blockIdx.z;  // mat*8 + h
  const float* W = (z < 8 ? W0 : (z < 16 ? W1 : W2)) + (size_t)(z & 7) * (4096 * 512);
  const int f0 = blockIdx.x * 64, u0 = blockIdx.y * 32;
  __shared__ float t[64][33];
  const int tid = threadIdx.x;
  {
    const int fi = tid >> 2, uu = (tid & 3) * 8;
    const float* src = W + (size_t)(f0 + fi) * 512 + u0 + uu;
    f32x4 v0 = *(const f32x4*)src;
    f32x4 v1 = *(const f32x4*)(src + 4);
    t[fi][uu] = v0.x; t[fi][uu + 1] = v0.y; t[fi][uu + 2] = v0.z; t[fi][uu + 3] = v0.w;
    t[fi][uu + 4] = v1.x; t[fi][uu + 5] = v1.y; t[fi][uu + 6] = v1.z; t[fi][uu + 7] = v1.w;
  }
  __syncthreads();
  {
    const int uo = tid >> 3, fo = (tid & 7) * 8;
    u16x8 o = { f2bf(t[fo][uo]),     f2bf(t[fo + 1][uo]), f2bf(t[fo + 2][uo]),
                f2bf(t[fo + 3][uo]), f2bf(t[fo + 4][uo]), f2bf(t[fo + 5][uo]),
                f2bf(t[fo + 6][uo]), f2bf(t[fo + 7][uo]) };
    *(u16x8*)&Wt[((size_t)z * 512 + u0 + uo) * 4096 + f0 + fo] = o;
  }
}

// ------------- 256x128-tile bf16 B^T GEMM, BK=64, 16x16x32 MFMA -------------
// 8 waves (512 thr), per-wave 64x64 sub-tile (wave -> 4x2 grid), acc[4][4].
// (R5 core geometry kept verbatim: l16/quad fragment reads + XOR chunk swizzle
//  slot(r,s)=s^(r&7) are empirically conflict-free -- do not change.)
// K-loop: 3-deep counted-vmcnt pipeline (T3/T4): raw s_barrier + inline-asm
// s_waitcnt vmcnt(N); never drains to 0 in steady state. 6 gld16/wave/K-tile
// (4xA + 2xB) -> steady-state wait vmcnt(12) = 2 tiles in flight.
// C[m][n] = sum_k A[m][k]*B[n][k]; A: M x K, B: N x K row-major bf16.
// MODE 4: z<16 -> bf16 rows into C0 + z*2^20 (ldc 512) [q|k];
//         z>=16 -> bf16 TRANSPOSED into C1 + (z-16)*2^20 (ldc 2048) [vt]
// MODE 2: bf16 exp2(acc*scale-c) into C0 + z*2^22 (ldc 2048) + atomic rowsum -> rs
// MODE 3: split-K=2 (z' = z + 8*kh): fp32 acc/rs[row] into (kh? C1 : C0) + z*2^20
template <int MODE>
__global__ __launch_bounds__(512, 2) void gemm_bt(
    const uint16_t* __restrict__ A, size_t sAz,
    const uint16_t* __restrict__ B, size_t sBz,
    void* __restrict__ C0, void* __restrict__ C1,
    int K, float scale, float* __restrict__ rs) {
  const int tid = threadIdx.x;
  const int wave = tid >> 6, lane = tid & 63;
  const int quad = lane >> 4, l16 = lane & 15;
  const int wrow = (wave >> 1) * 64, wcol = (wave & 1) * 64;
  const int m0 = blockIdx.y * 256, n0 = blockIdx.x * 128;
  int z = blockIdx.z, kh = 0, Kloop = K;
  if (MODE == 3) { kh = z >> 3; z &= 7; Kloop = K >> 1; }
  A += (size_t)z * sAz + (size_t)kh * Kloop;
  B += (size_t)z * sBz + (size_t)kh * Kloop;

  // 3 buffers: A 256x64, B 128x64 bf16 each -> 3*(32K+16K) = 144 KiB LDS
  __shared__ __align__(16) uint16_t lA[3 * 256 * 64];
  __shared__ __align__(16) uint16_t lB[3 * 128 * 64];

  f32x4 acc[4][4];
#pragma unroll
  for (int i = 0; i < 4; i++)
#pragma unroll
    for (int j = 0; j < 4; j++) acc[i][j] = f32x4{0.f, 0.f, 0.f, 0.f};

  // staging: per gld16 one wave covers 8 rows x 8 chunks (128 B/row).
  // lane l -> row rs0 + (l>>3), slot l&7, global chunk (l&7) ^ ((l>>3)&7)
  const int lrow = lane >> 3;
  const int cs = ((lane & 7) ^ (lrow & 7)) * 8;  // elems
  const int rs0 = wave * 8;
  const uint16_t* gA = A + (size_t)(m0 + rs0 + lrow) * K + cs;
  const uint16_t* gB = B + (size_t)(n0 + rs0 + lrow) * K + cs;
  const size_t row64 = (size_t)64 * K;  // 64 global rows (elems)
  uint16_t* sA = &lA[rs0 * 64];
  uint16_t* sB = &lB[rs0 * 64];

  const int nt = Kloop >> 6;  // K-tiles; all call sites have nt >= 3

  auto stage = [&](int t, int buf) {
    const uint16_t* ga = gA + (size_t)t * 64;
    const uint16_t* gb = gB + (size_t)t * 64;
    uint16_t* sa = sA + buf * (256 * 64);
    uint16_t* sb = sB + buf * (128 * 64);
#pragma unroll
    for (int g = 0; g < 4; g++)  // A: 8 waves x 8 rows x 4 = 256 rows
      gld16(ga + g * row64, sa + g * 4096);
#pragma unroll
    for (int g = 0; g < 2; g++)  // B: 8 waves x 8 rows x 2 = 128 rows
      gld16(gb + g * row64, sb + g * 4096);
  };

  auto compute = [&](int buf) {
    const uint16_t* la = &lA[buf * (256 * 64)];
    const uint16_t* lb = &lB[buf * (128 * 64)];
#pragma unroll
    for (int h = 0; h < 2; h++) {
      s16x8 af[4], bfr[4];
      const int fsw = (((h * 4 + quad) ^ (l16 & 7)) * 8);
#pragma unroll
      for (int i = 0; i < 4; i++)
        af[i] = *(const s16x8*)&la[(wrow + i * 16 + l16) * 64 + fsw];
#pragma unroll
      for (int j = 0; j < 4; j++)
        bfr[j] = *(const s16x8*)&lb[(wcol + j * 16 + l16) * 64 + fsw];
#pragma unroll
      for (int i = 0; i < 4; i++)
#pragma unroll
        for (int j = 0; j < 4; j++)
          acc[i][j] = __builtin_amdgcn_mfma_f32_16x16x32_bf16(af[i], bfr[j], acc[i][j], 0, 0, 0);
    }
  };

  // prologue: fill the 3-deep pipe, wait for tile 0 (12 = tiles 1,2 in flight)
  stage(0, 0);
  stage(1, 1);
  stage(2, 2);
  asm volatile("s_waitcnt vmcnt(12)" ::: "memory");
  __builtin_amdgcn_s_barrier();

  for (int t = 0;; ++t) {
    compute(t % 3);
    if (t == nt - 1) break;
    __builtin_amdgcn_s_barrier();  // all waves done reading buf t%3
    if (t + 3 < nt) {
      stage(t + 3, t % 3);
      asm volatile("s_waitcnt vmcnt(12)" ::: "memory");  // tile t+1 resident
    } else if (t + 3 == nt) {
      asm volatile("s_waitcnt vmcnt(6)" ::: "memory");   // tile t+1 resident
    } else {  // t == nt-2
      asm volatile("s_waitcnt vmcnt(0)" ::: "memory");
    }
    __builtin_amdgcn_s_barrier();  // every wave's share of t+1 visible
  }

  // C/D layout (verified m89/m91): col = lane&15, row = quad*4 + reg
  const int mb = m0 + wrow + quad * 4;
  const int nb = n0 + wcol + l16;
  if (MODE == 4) {
    if (z < 16) {
      uint16_t* C = (uint16_t*)C0 + ((size_t)z << 20);
#pragma unroll
      for (int i = 0; i < 4; i++)
#pragma unroll
        for (int j = 0; j < 4; j++)
#pragma unroll
          for (int r = 0; r < 4; r++)
            C[(size_t)(mb + i * 16 + r) * 512 + (nb + j * 16)] = f2bf(acc[i][j][r]);
    } else {
      uint16_t* C = (uint16_t*)C1 + ((size_t)(z - 16) << 20);
#pragma unroll
      for (int i = 0; i < 4; i++)
#pragma unroll
        for (int j = 0; j < 4; j++) {
          u16x4 o = { f2bf(acc[i][j][0]), f2bf(acc[i][j][1]),
                      f2bf(acc[i][j][2]), f2bf(acc[i][j][3]) };
          *(u16x4*)&C[(size_t)(nb + j * 16) * 2048 + (mb + i * 16)] = o;
        }
    }
  } else if (MODE == 2) {
    uint16_t* C = (uint16_t*)C0 + ((size_t)z << 22);
    float* rz = rs + (z << 11);
    float si[4][4];
#pragma unroll
    for (int i = 0; i < 4; i++)
#pragma unroll
      for (int r = 0; r < 4; r++) si[i][r] = 0.f;
#pragma unroll
    for (int i = 0; i < 4; i++)
#pragma unroll
      for (int j = 0; j < 4; j++)
#pragma unroll
        for (int r = 0; r < 4; r++) {
          // exp(s*scale-30) == exp2(s*scale*log2e - 30*log2e)
          float e = exp2f(fmaf(acc[i][j][r], scale, -43.2808512f));
          uint16_t hb = f2bf(e);
          C[(size_t)(mb + i * 16 + r) * 2048 + (nb + j * 16)] = hb;
          si[i][r] += bf2f(hb);  // sum the rounded values (matches stored P)
        }
    // reduce over the 16 l16 lanes (64 columns of this wave)
#pragma unroll
    for (int i = 0; i < 4; i++)
#pragma unroll
      for (int r = 0; r < 4; r++) {
        float s = si[i][r];
        s += __shfl_xor(s, 1);
        s += __shfl_xor(s, 2);
        s += __shfl_xor(s, 4);
        s += __shfl_xor(s, 8);
        si[i][r] = s;
      }
    if (l16 == 0) {
#pragma unroll
      for (int i = 0; i < 4; i++)
#pragma unroll
        for (int r = 0; r < 4; r++)
          atomicAdd(&rz[mb + i * 16 + r], si[i][r]);
    }
  } else {  // MODE 3 (split-K partial, scaled by 1/rowsum)
    float* C = (float*)(kh ? C1 : C0) + ((size_t)z << 20);
    const float* rz = rs + (z << 11);
#pragma unroll
    for (int i = 0; i < 4; i++)
#pragma unroll
      for (int r = 0; r < 4; r++) {
        float w = 1.0f / rz[mb + i * 16 + r];
#pragma unroll
        for (int j = 0; j < 4; j++)
          C[(size_t)(mb + i * 16 + r) * 512 + (nb + j * 16)] = acc[i][j][r] * w;
      }
  }
}

// ------------- K6: out = concat(av0+av1) @ Wo (32x32) -------------
__global__ __launch_bounds__(256) void out_proj(const float* __restrict__ av0,
                                                const float* __restrict__ av1,
                                                const float* __restrict__ Wo,
                                                float* __restrict__ out) {
  __shared__ float lw[1024];
  const int tid = threadIdx.x;
#pragma unroll
  for (int i = 0; i < 4; i++) lw[tid + i * 256] = Wo[tid + i * 256];
  __syncthreads();
  const int p = blockIdx.x * 256 + tid;  // b*128 + n
  const int b = p >> 7, n = p & 127;
  float c[32];
#pragma unroll
  for (int hh = 0; hh < 8; hh++) {
    size_t idx = ((size_t)hh * 2048 + b) * 512 + n * 4;
    f32x4 v = *(const f32x4*)(av0 + idx);
    f32x4 w = *(const f32x4*)(av1 + idx);
    c[hh * 4] = v.x + w.x; c[hh * 4 + 1] = v.y + w.y;
    c[hh * 4 + 2] = v.z + w.z; c[hh * 4 + 3] = v.w + w.w;
  }
  float o[32];
#pragma unroll
  for (int d = 0; d < 32; d++) o[d] = 0.f;
#pragma unroll
  for (int j = 0; j < 32; j++) {
    float cj = c[j];
#pragma unroll
    for (int d = 0; d < 32; d++) o[d] = fmaf(cj, lw[j * 32 + d], o[d]);
  }
  float* dst = out + (size_t)p * 32;
#pragma unroll
  for (int i = 0; i < 8; i++) {
    f32x4 v = { o[i * 4], o[i * 4 + 1], o[i * 4 + 2], o[i * 4 + 3] };
    *(f32x4*)(dst + i * 4) = v;
  }
}

extern "C" void kernel_launch(void* const* d_in, const int* in_sizes, int n_in,
                              void* d_out, int out_size, void* d_ws, size_t ws_size,
                              hipStream_t stream) {
  const float* x  = (const float*)d_in[0];
  const float* Wq = (const float*)d_in[1];
  const float* Wk = (const float*)d_in[2];
  const float* Wv = (const float*)d_in[3];
  const float* Wo = (const float*)d_in[4];
  float* out = (float*)d_out;

  // ws layout (bytes), total 167,837,696:
  //   [0, 100663296): Wt bf16 (24 x 512 x 4096) -- dead after projections;
  //     then: P_u bf16 (8x2048x2048) at 0, av0 fp32 (8x2048x512) at 67108864
  //   [100663296): xf bf16, [117440512): q bf16, [134217728): k bf16
  //     (q,k dead after QK^T -> av1 fp32 (33.5 MB) overlays them during PV)
  //   [150994944): vt bf16, [167772160): rs fp32 (8x2048)
  uint8_t* ws = (uint8_t*)d_ws;
  uint16_t* Wt  = (uint16_t*)(ws);
  uint16_t* P   = (uint16_t*)(ws);
  float*    av0 = (float*)(ws + 67108864);
  uint16_t* xf  = (uint16_t*)(ws + 100663296);
  uint16_t* q   = (uint16_t*)(ws + 117440512);
  float*    av1 = (float*)(ws + 117440512);
  uint16_t* vt  = (uint16_t*)(ws + 150994944);
  float*    rs  = (float*)(ws + 167772160);

  const size_t WtH = (size_t)512 * 4096;  // per-head Wt elements
  // qk^T scale folded with log2(e) for exp2: 32^-0.5 * 1.4426950408889634
  const float scale2 = 0.17677669529663687f * 1.4426950408889634f;

  cvt_x<<<8192, 256, 0, stream>>>(x, xf, rs);
  wtrans<<<dim3(64, 16, 24), 256, 0, stream>>>(Wq, Wk, Wv, Wt);

  // fused q|k|v projections: M=2048, N=512, K=4096, z=0..23 -> 768 blocks (3x256)
  gemm_bt<4><<<dim3(4, 8, 24), 512, 0, stream>>>(
      xf, 0, Wt, WtH, q, vt, 4096, 0.f, nullptr);

  // P_u = exp2(q k^T * scale2 - 30*log2e) + fused rowsum: M=N=2048, K=512
  gemm_bt<2><<<dim3(16, 8, 8), 512, 0, stream>>>(
      q, (size_t)2048 * 512, q + (size_t)8 * 2048 * 512, (size_t)2048 * 512,
      P, nullptr, 512, scale2, rs);

  // av = (P_u @ v) / rowsum, split-K=2 (z = head + 8*khalf): M=2048, N=512, K=2048
  gemm_bt<3><<<dim3(4, 8, 16), 512, 0, stream>>>(
      P, (size_t)2048 * 2048, vt, (size_t)512 * 2048,
      av0, av1, 2048, 0.f, rs);

  out_proj<<<1024, 256, 0, stream>>>(av0, av1, Wo, out);
}

// Round 3
// 550.067 us; speedup vs baseline: 1.1724x; 1.1724x over previous
//
#include <hip/hip_runtime.h>
#include <stdint.h>
#include <math.h>

typedef short    s16x8 __attribute__((ext_vector_type(8)));
typedef float    f32x4 __attribute__((ext_vector_type(4)));
typedef uint32_t u32x4 __attribute__((ext_vector_type(4)));
typedef unsigned short u16x4 __attribute__((ext_vector_type(4)));
typedef unsigned short u16x8 __attribute__((ext_vector_type(8)));

__device__ __forceinline__ uint16_t f2bf(float f) {
  union { float f; uint32_t u; } v; v.f = f;
  uint32_t r = v.u + 0x7fffu + ((v.u >> 16) & 1u);
  return (uint16_t)(r >> 16);
}
__device__ __forceinline__ float bf2f(uint16_t h) {
  union { uint32_t u; float f; } v; v.u = ((uint32_t)h) << 16;
  return v.f;
}

// async global->LDS, 16B per lane; LDS dest = wave-uniform base + lane*16
__device__ __forceinline__ void gld16(const void* g, void* l) {
  __builtin_amdgcn_global_load_lds(
      (const __attribute__((address_space(1))) void*)g,
      (__attribute__((address_space(3))) void*)l, 16, 0, 0);
}

// ---------------- K0: x fp32 -> xf bf16 (2048 x 4096); also zeroes rs ----------------
__global__ __launch_bounds__(256) void cvt_x(const float* __restrict__ x,
                                             uint16_t* __restrict__ xf,
                                             float* __restrict__ rs) {
  if (blockIdx.x < 64) rs[blockIdx.x * 256 + threadIdx.x] = 0.f;
  size_t i = ((size_t)blockIdx.x * 256 + threadIdx.x) * 4;
  f32x4 v = *(const f32x4*)(x + i);
  u16x4 o = { f2bf(v.x), f2bf(v.y), f2bf(v.z), f2bf(v.w) };
  *(u16x4*)(xf + i) = o;
}

// ------------- K1: W (3 x H x 4096 x 512 fp32) -> Wt (24 x 512 x 4096 bf16) -------------
__global__ __launch_bounds__(256) void wtrans(const float* __restrict__ W0,
                                              const float* __restrict__ W1,
                                              const float* __restrict__ W2,
                                              uint16_t* __restrict__ Wt) {
  const int z = blockIdx.z;  // mat*8 + h
  const float* W = (z < 8 ? W0 : (z < 16 ? W1 : W2)) + (size_t)(z & 7) * (4096 * 512);
  const int f0 = blockIdx.x * 64, u0 = blockIdx.y * 32;
  __shared__ float t[64][33];
  const int tid = threadIdx.x;
  {
    const int fi = tid >> 2, uu = (tid & 3) * 8;
    const float* src = W + (size_t)(f0 + fi) * 512 + u0 + uu;
    f32x4 v0 = *(const f32x4*)src;
    f32x4 v1 = *(const f32x4*)(src + 4);
    t[fi][uu] = v0.x; t[fi][uu + 1] = v0.y; t[fi][uu + 2] = v0.z; t[fi][uu + 3] = v0.w;
    t[fi][uu + 4] = v1.x; t[fi][uu + 5] = v1.y; t[fi][uu + 6] = v1.z; t[fi][uu + 7] = v1.w;
  }
  __syncthreads();
  {
    const int uo = tid >> 3, fo = (tid & 7) * 8;
    u16x8 o = { f2bf(t[fo][uo]),     f2bf(t[fo + 1][uo]), f2bf(t[fo + 2][uo]),
                f2bf(t[fo + 3][uo]), f2bf(t[fo + 4][uo]), f2bf(t[fo + 5][uo]),
                f2bf(t[fo + 6][uo]), f2bf(t[fo + 7][uo]) };
    *(u16x8*)&Wt[((size_t)z * 512 + u0 + uo) * 4096 + f0 + fo] = o;
  }
}

// ------------- 256x256-tile bf16 B^T GEMM, 8-phase pipeline (m201 template) -------------
// 8 waves (512 thr) as 2(M)x4(N); per-wave output 128x64, acc[8][4] of 16x16.
// LDS 128 KiB = 2 buf x {A: 2 half x 128x64, B: 2 half x 128x64} bf16.
// (R5 fragment geometry verbatim: XOR chunk swizzle slot(r,s)=s^(r&7); staging
//  via pre-swizzled global src so LDS dest stays linear for global_load_lds.)
// Per K-tile (BK=64), 4 phases = 4 output quadrants (ih,jh) of 64rows x 32cols
// x K=64 each (16 MFMA). Phase: {ds_read frags | stage 1 half-tile} -> barrier
// -> lgkmcnt(0) -> setprio(1) 16xMFMA setprio(0) -> barrier. Counted vmcnt(4)
// only at phases 4/8 (2 half-tiles stay in flight; never drain in main loop).
// Region lifetimes per tile in phases P0-P3: B-halves dead after P1, A-halves
// after P2 -> stage slots: ph2/ph3 = Bh0/Bh1(t+2); ph4/ph5 = Ah0/Ah1(t+2);
// ph6/ph7 = Bh0/Bh1(t+3); ph0/ph1 = Ah0/Ah1(t+1, other buffer).
// MODE 4: z<16 -> bf16 rows into C0 + z*2^20 (ldc 512) [q|k];
//         z>=16 -> bf16 TRANSPOSED into C1 + (z-16)*2^20 (ldc 2048) [vt]
// MODE 2: bf16 exp2(acc*scale-c) into C0 + z*2^22 (ldc 2048) + atomic rowsum -> rs
// MODE 3: split-K=2 (z' = z + 8*kh): fp32 acc/rs[row] into (kh? C1 : C0) + z*2^20
template <int MODE>
__global__ __launch_bounds__(512, 2) void gemm_bt(
    const uint16_t* __restrict__ A, size_t sAz,
    const uint16_t* __restrict__ B, size_t sBz,
    void* __restrict__ C0, void* __restrict__ C1,
    int K, float scale, float* __restrict__ rs) {
  const int tid = threadIdx.x;
  const int wave = tid >> 6, lane = tid & 63;
  const int quad = lane >> 4, l16 = lane & 15;
  const int wm = wave >> 2, wn = wave & 3;      // 2(M) x 4(N) wave grid
  const int wnh = wn >> 1, wnl = wn & 1;
  const int m0 = blockIdx.y * 256, n0 = blockIdx.x * 256;
  int z = blockIdx.z, kh = 0, Kloop = K;
  if (MODE == 3) { kh = z >> 3; z &= 7; Kloop = K >> 1; }
  A += (size_t)z * sAz + (size_t)kh * Kloop;
  B += (size_t)z * sBz + (size_t)kh * Kloop;

  // [buf][mat A=0/B=1][half][128 rows x 64 elems]; 65536 elems = 128 KiB
  __shared__ __align__(16) uint16_t lds[65536];

  f32x4 acc[8][4];
#pragma unroll
  for (int i = 0; i < 8; i++)
#pragma unroll
    for (int j = 0; j < 4; j++) acc[i][j] = f32x4{0.f, 0.f, 0.f, 0.f};
  s16x8 af[4][2], bq0[2][2], bq1[2][2];

  // staging: per gld16 one wave covers 8 rows x 8 chunks (128 B/row), 8 waves
  // cover 64 rows/round, 2 rounds per 128-row half-tile.
  // lane l -> row (l>>3), slot l&7, global chunk (l&7) ^ ((l>>3)&7)
  const int lrow = lane >> 3;
  const int cs = ((lane & 7) ^ (lrow & 7)) * 8;  // elems
  const uint16_t* gA = A + (size_t)(m0 + wave * 8 + lrow) * K + cs;
  const uint16_t* gB = B + (size_t)(n0 + wave * 8 + lrow) * K + cs;
  const size_t rs64 = (size_t)64 * K;  // 64 global rows (elems)
  const int stW = wave * 512;          // wave-uniform LDS offset (elems)

#define STAGE(buf, mat, half, t)                                               \
  do {                                                                         \
    const uint16_t* gsrc =                                                     \
        ((mat) ? gB : gA) + (size_t)(half) * 128 * K + (size_t)(t) * 64;       \
    uint16_t* sdst =                                                           \
        &lds[(buf) * 32768 + (mat) * 16384 + (half) * 8192 + stW];             \
    gld16(gsrc, sdst);                                                         \
    gld16(gsrc + rs64, sdst + 4096);                                           \
  } while (0)

#define LOAD_A(buf, ih)                                                        \
  do {                                                                         \
    const uint16_t* ba = &lds[(buf) * 32768 + wm * 8192];                      \
    _Pragma("unroll") for (int i_ = 0; i_ < 4; i_++)                           \
      _Pragma("unroll") for (int k_ = 0; k_ < 2; k_++)                         \
        af[i_][k_] = *(const s16x8*)&ba[((ih) * 64 + i_ * 16 + l16) * 64 +     \
                                        ((k_ * 4 + quad) ^ (l16 & 7)) * 8];    \
  } while (0)

#define LOAD_B(buf, jh, bq)                                                    \
  do {                                                                         \
    const uint16_t* bb = &lds[(buf) * 32768 + 16384 + wnh * 8192];             \
    _Pragma("unroll") for (int j_ = 0; j_ < 2; j_++)                           \
      _Pragma("unroll") for (int k_ = 0; k_ < 2; k_++)                         \
        bq[j_][k_] = *(const s16x8*)&bb[(wnl * 64 + (jh) * 32 + j_ * 16 + l16) \
                                            * 64 +                             \
                                        ((k_ * 4 + quad) ^ (l16 & 7)) * 8];    \
  } while (0)

#define MMQ(ih, jh, bq)                                                        \
  do {                                                                         \
    __builtin_amdgcn_s_setprio(1);                                             \
    _Pragma("unroll") for (int i_ = 0; i_ < 4; i_++)                           \
      _Pragma("unroll") for (int j_ = 0; j_ < 2; j_++)                         \
        _Pragma("unroll") for (int k_ = 0; k_ < 2; k_++)                       \
          acc[(ih) * 4 + i_][(jh) * 2 + j_] =                                  \
              __builtin_amdgcn_mfma_f32_16x16x32_bf16(                         \
                  af[i_][k_], bq[j_][k_],                                      \
                  acc[(ih) * 4 + i_][(jh) * 2 + j_], 0, 0, 0);                 \
    __builtin_amdgcn_s_setprio(0);                                             \
  } while (0)

#define BAR __builtin_amdgcn_s_barrier()
#define LGKM0 asm volatile("s_waitcnt lgkmcnt(0)" ::: "memory")
#define VMW(n) asm volatile("s_waitcnt vmcnt(" #n ")" ::: "memory")

  // prologue: tile0 {Bh0,Bh1,Ah0,Ah1}, tile1 {Bh0,Bh1}; keep last 2 in flight
  STAGE(0, 1, 0, 0); STAGE(0, 1, 1, 0);
  STAGE(0, 0, 0, 0); STAGE(0, 0, 1, 0);
  STAGE(1, 1, 0, 1); STAGE(1, 1, 1, 1);
  VMW(4); BAR;

  const int L = (Kloop >> 7) - 1;  // nt/2 - 1 main iterations (nt even, >=8)
  for (int it = 0; it < L; ++it) {
    const int t1 = 2 * it + 1, t2 = 2 * it + 2, t3 = 2 * it + 3;
    // ph0 (tile 2it, quadrant 0,0)
    LOAD_A(0, 0); LOAD_B(0, 0, bq0); STAGE(1, 0, 0, t1);
    BAR; LGKM0; MMQ(0, 0, bq0); BAR;
    // ph1 (q 0,1)
    LOAD_B(0, 1, bq1); STAGE(1, 0, 1, t1);
    BAR; LGKM0; MMQ(0, 1, bq1); BAR;
    // ph2 (q 1,0)
    LOAD_A(0, 1); STAGE(0, 1, 0, t2);
    BAR; LGKM0; MMQ(1, 0, bq0); BAR;
    // ph3 (q 1,1) + tile boundary
    STAGE(0, 1, 1, t2);
    BAR; LGKM0; MMQ(1, 1, bq1); VMW(4); BAR;
    // ph4 (tile 2it+1, q 0,0)
    LOAD_A(1, 0); LOAD_B(1, 0, bq0); STAGE(0, 0, 0, t2);
    BAR; LGKM0; MMQ(0, 0, bq0); BAR;
    // ph5 (q 0,1)
    LOAD_B(1, 1, bq1); STAGE(0, 0, 1, t2);
    BAR; LGKM0; MMQ(0, 1, bq1); BAR;
    // ph6 (q 1,0)
    LOAD_A(1, 1); STAGE(1, 1, 0, t3);
    BAR; LGKM0; MMQ(1, 0, bq0); BAR;
    // ph7 (q 1,1) + tile boundary
    STAGE(1, 1, 1, t3);
    BAR; LGKM0; MMQ(1, 1, bq1); VMW(4); BAR;
  }
  // tail iteration (tiles 2L, 2L+1): finish staging 2L+1, no further prefetch
  {
    const int t1 = 2 * L + 1;
    LOAD_A(0, 0); LOAD_B(0, 0, bq0); STAGE(1, 0, 0, t1);
    BAR; LGKM0; MMQ(0, 0, bq0); BAR;
    LOAD_B(0, 1, bq1); STAGE(1, 0, 1, t1);
    BAR; LGKM0; MMQ(0, 1, bq1); BAR;
    LOAD_A(0, 1);
    BAR; LGKM0; MMQ(1, 0, bq0); BAR;
    MMQ(1, 1, bq1); VMW(0); BAR;
    LOAD_A(1, 0); LOAD_B(1, 0, bq0); LGKM0; MMQ(0, 0, bq0);
    LOAD_B(1, 1, bq1); LGKM0; MMQ(0, 1, bq1);
    LOAD_A(1, 1); LGKM0; MMQ(1, 0, bq0);
    MMQ(1, 1, bq1);
  }

  // C/D layout (verified m89/m91): col = lane&15, row = quad*4 + reg
  const int mb = m0 + wm * 128 + quad * 4;
  const int nb = n0 + wn * 64 + l16;
  if (MODE == 4) {
    if (z < 16) {
      uint16_t* C = (uint16_t*)C0 + ((size_t)z << 20);
#pragma unroll
      for (int i = 0; i < 8; i++)
#pragma unroll
        for (int j = 0; j < 4; j++)
#pragma unroll
          for (int r = 0; r < 4; r++)
            C[(size_t)(mb + i * 16 + r) * 512 + (nb + j * 16)] = f2bf(acc[i][j][r]);
    } else {
      uint16_t* C = (uint16_t*)C1 + ((size_t)(z - 16) << 20);
#pragma unroll
      for (int i = 0; i < 8; i++)
#pragma unroll
        for (int j = 0; j < 4; j++) {
          u16x4 o = { f2bf(acc[i][j][0]), f2bf(acc[i][j][1]),
                      f2bf(acc[i][j][2]), f2bf(acc[i][j][3]) };
          *(u16x4*)&C[(size_t)(nb + j * 16) * 2048 + (mb + i * 16)] = o;
        }
    }
  } else if (MODE == 2) {
    uint16_t* C = (uint16_t*)C0 + ((size_t)z << 22);
    float* rz = rs + (z << 11);
    float si[8][4];
#pragma unroll
    for (int i = 0; i < 8; i++)
#pragma unroll
      for (int r = 0; r < 4; r++) si[i][r] = 0.f;
#pragma unroll
    for (int i = 0; i < 8; i++)
#pragma unroll
      for (int j = 0; j < 4; j++)
#pragma unroll
        for (int r = 0; r < 4; r++) {
          // exp(s*scale-30) == exp2(s*scale*log2e - 30*log2e)
          float e = exp2f(fmaf(acc[i][j][r], scale, -43.2808512f));
          uint16_t hb = f2bf(e);
          C[(size_t)(mb + i * 16 + r) * 2048 + (nb + j * 16)] = hb;
          si[i][r] += bf2f(hb);  // sum the rounded values (matches stored P)
        }
    // reduce over the 16 l16 lanes (64 columns of this wave)
#pragma unroll
    for (int i = 0; i < 8; i++)
#pragma unroll
      for (int r = 0; r < 4; r++) {
        float s = si[i][r];
        s += __shfl_xor(s, 1);
        s += __shfl_xor(s, 2);
        s += __shfl_xor(s, 4);
        s += __shfl_xor(s, 8);
        si[i][r] = s;
      }
    if (l16 == 0) {
#pragma unroll
      for (int i = 0; i < 8; i++)
#pragma unroll
        for (int r = 0; r < 4; r++)
          atomicAdd(&rz[mb + i * 16 + r], si[i][r]);
    }
  } else {  // MODE 3 (split-K partial, scaled by 1/rowsum)
    float* C = (float*)(kh ? C1 : C0) + ((size_t)z << 20);
    const float* rz = rs + (z << 11);
#pragma unroll
    for (int i = 0; i < 8; i++)
#pragma unroll
      for (int r = 0; r < 4; r++) {
        float w = 1.0f / rz[mb + i * 16 + r];
#pragma unroll
        for (int j = 0; j < 4; j++)
          C[(size_t)(mb + i * 16 + r) * 512 + (nb + j * 16)] = acc[i][j][r] * w;
      }
  }
#undef STAGE
#undef LOAD_A
#undef LOAD_B
#undef MMQ
#undef BAR
#undef LGKM0
#undef VMW
}

// ------------- K6: out = concat(av0+av1) @ Wo (32x32) -------------
__global__ __launch_bounds__(256) void out_proj(const float* __restrict__ av0,
                                                const float* __restrict__ av1,
                                                const float* __restrict__ Wo,
                                                float* __restrict__ out) {
  __shared__ float lw[1024];
  const int tid = threadIdx.x;
#pragma unroll
  for (int i = 0; i < 4; i++) lw[tid + i * 256] = Wo[tid + i * 256];
  __syncthreads();
  const int p = blockIdx.x * 256 + tid;  // b*128 + n
  const int b = p >> 7, n = p & 127;
  float c[32];
#pragma unroll
  for (int hh = 0; hh < 8; hh++) {
    size_t idx = ((size_t)hh * 2048 + b) * 512 + n * 4;
    f32x4 v = *(const f32x4*)(av0 + idx);
    f32x4 w = *(const f32x4*)(av1 + idx);
    c[hh * 4] = v.x + w.x; c[hh * 4 + 1] = v.y + w.y;
    c[hh * 4 + 2] = v.z + w.z; c[hh * 4 + 3] = v.w + w.w;
  }
  float o[32];
#pragma unroll
  for (int d = 0; d < 32; d++) o[d] = 0.f;
#pragma unroll
  for (int j = 0; j < 32; j++) {
    float cj = c[j];
#pragma unroll
    for (int d = 0; d < 32; d++) o[d] = fmaf(cj, lw[j * 32 + d], o[d]);
  }
  float* dst = out + (size_t)p * 32;
#pragma unroll
  for (int i = 0; i < 8; i++) {
    f32x4 v = { o[i * 4], o[i * 4 + 1], o[i * 4 + 2], o[i * 4 + 3] };
    *(f32x4*)(dst + i * 4) = v;
  }
}

extern "C" void kernel_launch(void* const* d_in, const int* in_sizes, int n_in,
                              void* d_out, int out_size, void* d_ws, size_t ws_size,
                              hipStream_t stream) {
  const float* x  = (const float*)d_in[0];
  const float* Wq = (const float*)d_in[1];
  const float* Wk = (const float*)d_in[2];
  const float* Wv = (const float*)d_in[3];
  const float* Wo = (const float*)d_in[4];
  float* out = (float*)d_out;

  // ws layout (bytes), total 167,837,696:
  //   [0, 100663296): Wt bf16 (24 x 512 x 4096) -- dead after projections;
  //     then: P_u bf16 (8x2048x2048) at 0, av0 fp32 (8x2048x512) at 67108864
  //   [100663296): xf bf16, [117440512): q bf16, [134217728): k bf16
  //     (q,k dead after QK^T -> av1 fp32 (33.5 MB) overlays them during PV)
  //   [150994944): vt bf16, [167772160): rs fp32 (8x2048)
  uint8_t* ws = (uint8_t*)d_ws;
  uint16_t* Wt  = (uint16_t*)(ws);
  uint16_t* P   = (uint16_t*)(ws);
  float*    av0 = (float*)(ws + 67108864);
  uint16_t* xf  = (uint16_t*)(ws + 100663296);
  uint16_t* q   = (uint16_t*)(ws + 117440512);
  float*    av1 = (float*)(ws + 117440512);
  uint16_t* vt  = (uint16_t*)(ws + 150994944);
  float*    rs  = (float*)(ws + 167772160);

  const size_t WtH = (size_t)512 * 4096;  // per-head Wt elements
  // qk^T scale folded with log2(e) for exp2: 32^-0.5 * 1.4426950408889634
  const float scale2 = 0.17677669529663687f * 1.4426950408889634f;

  cvt_x<<<8192, 256, 0, stream>>>(x, xf, rs);
  wtrans<<<dim3(64, 16, 24), 256, 0, stream>>>(Wq, Wk, Wv, Wt);

  // fused q|k|v projections: M=2048, N=512, K=4096, z=0..23 -> 384 blocks
  gemm_bt<4><<<dim3(2, 8, 24), 512, 0, stream>>>(
      xf, 0, Wt, WtH, q, vt, 4096, 0.f, nullptr);

  // P_u = exp2(q k^T * scale2 - 30*log2e) + fused rowsum: M=N=2048, K=512
  gemm_bt<2><<<dim3(8, 8, 8), 512, 0, stream>>>(
      q, (size_t)2048 * 512, q + (size_t)8 * 2048 * 512, (size_t)2048 * 512,
      P, nullptr, 512, scale2, rs);

  // av = (P_u @ v) / rowsum, split-K=2 (z = head + 8*khalf): M=2048, N=512, K=2048
  gemm_bt<3><<<dim3(2, 8, 16), 512, 0, stream>>>(
      P, (size_t)2048 * 2048, vt, (size_t)512 * 2048,
      av0, av1, 2048, 0.f, rs);

  out_proj<<<1024, 256, 0, stream>>>(av0, av1, Wo, out);
}